// Round 10
// baseline (1609.504 us; speedup 1.0000x reference)
//
#include <hip/hip_runtime.h>
#include <hip/hip_bf16.h>

#define HH 361
#define WW 720
#define HWP (HH*WW)          // 259920
#define CIN 11
#define CC 32
#define HD 16
#define EE 10
#define NBATCH ((HWP + 63) / 64)   // 4062
#define LN_EPS 1e-5f
#define SELU_ALPHA 1.6732632423543772f
#define SELU_SCALE 1.0507009873554805f
#define SELU_SA (SELU_SCALE * SELU_ALPHA)

typedef float f32x4 __attribute__((ext_vector_type(4)));

// bf16 helpers (round-to-nearest-even pack; cheap unpacks from packed dwords)
static __device__ __forceinline__ unsigned int f2bf(float f) {
    unsigned int u = __float_as_uint(f);
    return (u + 0x7FFFu + ((u >> 16) & 1u)) >> 16;
}
static __device__ __forceinline__ float bflo(unsigned int u) {
    return __uint_as_float(u << 16);
}
static __device__ __forceinline__ float bfhi(unsigned int u) {
    return __uint_as_float(u & 0xffff0000u);
}
static __device__ __forceinline__ float selu_f(float v) {
    // fast SELU: v_exp_f32-based; abs err <= ~2e-6, invisible vs bf16 storage
    return v > 0.f ? SELU_SCALE * v : SELU_SA * (__expf(v) - 1.f);
}

// ---------------- zero accumulators ----------------
__global__ void zero_kernel(float* __restrict__ p) {
    int t = blockIdx.x * 256 + threadIdx.x;
    if (t < 40 + HD * EE * EE) p[t] = 0.f;
}

// ---------------- conv 5x5 + SELU + LN partials, scalar fp32, VALU-optimized ----------------
// grid (12, 23, 10*2), block (64,4). z = e*2 + half. Thread = 1 col x 4 rows x 16 ch.
// Weights in LDS [ci*25+k25][16]; per (ci,kh,kw) 4 broadcast ds_read_b128 feed 64 FMAs.
// Interior blocks (x 1..10, y 1..21, 76% of work): guard-free float4+scalar row loads
// from one base pointer (16 load insts/ci vs 40, zero cndmasks).
__global__ __launch_bounds__(256) void conv_selu_kernel(
    const float* __restrict__ inp, const float* __restrict__ emb_w,
    const float* __restrict__ emb_b, unsigned short* __restrict__ xout,
    float* __restrict__ stats)
{
    __shared__ float wlds[CIN * 25 * 16];   // 17.6 KB
    __shared__ float bsm[16];
    __shared__ float red[8];
    const int z = blockIdx.z;
    const int e = z >> 1, half = z & 1;
    const int tid = threadIdx.y * 64 + threadIdx.x;
    for (int t = tid; t < CIN * 25 * 16; t += 256) {
        int u = t & 15; int rest = t >> 4; int k25 = rest % 25; int ci = rest / 25;
        wlds[t] = emb_w[((half * 16 + u) * CIN + ci) * 25 + k25];
    }
    if (tid < 16) bsm[tid] = emb_b[half * 16 + tid];
    __syncthreads();

    const int w  = blockIdx.x * 64 + threadIdx.x;
    const int h0 = blockIdx.y * 16 + threadIdx.y * 4;
    const bool active = (w < WW);
    const bool interior = (blockIdx.x >= 1) && (blockIdx.x <= 10) &&
                          (blockIdx.y >= 1) && (blockIdx.y <= 21);

    int wl[5];
    if (active) {
        #pragma unroll
        for (int d = 0; d < 5; ++d) {
            int ww = w + d - 2; if (ww < 0) ww += WW; if (ww >= WW) ww -= WW; wl[d] = ww;
        }
    }

    float acc[4][16];
    #pragma unroll
    for (int hs = 0; hs < 4; ++hs)
        #pragma unroll
        for (int c = 0; c < 16; ++c) acc[hs][c] = bsm[c];

    if (active) {
        #pragma unroll 1
        for (int ci = 0; ci < CIN; ++ci) {
            const float* ip = inp + ((size_t)(e * CIN + ci)) * HWP;
            float in[8][5];
            if (interior) {
                // rows h0-2..h0+5 all valid; w-2..w+2 no wrap: float4 + scalar per row
                const float* rp2 = ip + (size_t)(h0 - 2) * WW + (w - 2);
                #pragma unroll
                for (int r = 0; r < 8; ++r) {
                    float4 q = *(const float4*)rp2;
                    in[r][0] = q.x; in[r][1] = q.y; in[r][2] = q.z; in[r][3] = q.w;
                    in[r][4] = rp2[4];
                    rp2 += WW;
                }
            } else {
                #pragma unroll
                for (int r = 0; r < 8; ++r) {
                    int hh = h0 + r - 2;
                    bool v = (hh >= 0 && hh < HH);
                    const float* rp = ip + (size_t)hh * WW;
                    #pragma unroll
                    for (int d = 0; d < 5; ++d) in[r][d] = v ? rp[wl[d]] : 0.f;
                }
            }
            #pragma unroll
            for (int kh = 0; kh < 5; ++kh) {
                #pragma unroll
                for (int kw = 0; kw < 5; ++kw) {
                    const float* wp = &wlds[(ci * 25 + kh * 5 + kw) * 16];
                    const float4 w0 = *(const float4*)(wp);
                    const float4 w1 = *(const float4*)(wp + 4);
                    const float4 w2 = *(const float4*)(wp + 8);
                    const float4 w3 = *(const float4*)(wp + 12);
                    #pragma unroll
                    for (int hs = 0; hs < 4; ++hs) {
                        const float iv = in[hs + kh][kw];
                        acc[hs][0]  = fmaf(iv, w0.x, acc[hs][0]);
                        acc[hs][1]  = fmaf(iv, w0.y, acc[hs][1]);
                        acc[hs][2]  = fmaf(iv, w0.z, acc[hs][2]);
                        acc[hs][3]  = fmaf(iv, w0.w, acc[hs][3]);
                        acc[hs][4]  = fmaf(iv, w1.x, acc[hs][4]);
                        acc[hs][5]  = fmaf(iv, w1.y, acc[hs][5]);
                        acc[hs][6]  = fmaf(iv, w1.z, acc[hs][6]);
                        acc[hs][7]  = fmaf(iv, w1.w, acc[hs][7]);
                        acc[hs][8]  = fmaf(iv, w2.x, acc[hs][8]);
                        acc[hs][9]  = fmaf(iv, w2.y, acc[hs][9]);
                        acc[hs][10] = fmaf(iv, w2.z, acc[hs][10]);
                        acc[hs][11] = fmaf(iv, w2.w, acc[hs][11]);
                        acc[hs][12] = fmaf(iv, w3.x, acc[hs][12]);
                        acc[hs][13] = fmaf(iv, w3.y, acc[hs][13]);
                        acc[hs][14] = fmaf(iv, w3.z, acc[hs][14]);
                        acc[hs][15] = fmaf(iv, w3.w, acc[hs][15]);
                    }
                }
            }
        }
    }

    // ---- epilogue: SELU + pack bf16 + stats
    float s = 0.f, s2 = 0.f;
    #pragma unroll
    for (int hs = 0; hs < 4; ++hs) {
        const int h = h0 + hs;
        if (active && h < HH) {
            unsigned int pk[8];
            #pragma unroll
            for (int c = 0; c < 16; c += 2) {
                float v0 = selu_f(acc[hs][c]);
                float v1 = selu_f(acc[hs][c + 1]);
                s += v0 + v1; s2 = fmaf(v0, v0, s2); s2 = fmaf(v1, v1, s2);
                pk[c >> 1] = f2bf(v0) | (f2bf(v1) << 16);
            }
            uint4* dst = (uint4*)(xout + ((size_t)e * HWP + (size_t)h * WW + w) * CC + half * 16);
            dst[0] = make_uint4(pk[0], pk[1], pk[2], pk[3]);
            dst[1] = make_uint4(pk[4], pk[5], pk[6], pk[7]);
        }
    }
    #pragma unroll
    for (int off = 32; off; off >>= 1) { s += __shfl_down(s, off); s2 += __shfl_down(s2, off); }
    if ((tid & 63) == 0) { red[tid >> 6] = s; red[4 + (tid >> 6)] = s2; }
    __syncthreads();
    if (tid == 0) {
        atomicAdd(&stats[e], red[0] + red[1] + red[2] + red[3]);
        atomicAdd(&stats[EE + e], red[4] + red[5] + red[6] + red[7]);
    }
}

// ---------------- finalize LN stats ----------------
__global__ void ln_stats_kernel(float* __restrict__ stats) {
    int e = threadIdx.x;
    if (e < EE) {
        const float N = (float)CC * (float)HWP;
        float mu = stats[e] / N;
        float var = stats[EE + e] / N - mu * mu;
        stats[2 * EE + e] = mu;
        stats[3 * EE + e] = rsqrtf(var + LN_EPS);
    }
}

// ---------------- fused k,q + scores ----------------
__global__ __launch_bounds__(256) void scores_fused_kernel(
    const unsigned short* __restrict__ x, const float* __restrict__ ln_w,
    const float* __restrict__ ln_b, const float* __restrict__ wk,
    const float* __restrict__ wq, const float* __restrict__ stats,
    float* __restrict__ sacc)
{
    __shared__ float wksT[CC * HD], wqsT[CC * HD];   // [ch][c]
    __shared__ unsigned int stage[64][164];          // k at [e*8+d], q at [80+e*8+d]
    for (int t = threadIdx.x; t < CC * HD; t += 256) {
        int ch = t >> 4, c = t & 15;
        wksT[t] = wk[c * CC + ch];
        wqsT[t] = wq[c * CC + ch];
    }
    float mu[EE], rs[EE];
    #pragma unroll
    for (int e2 = 0; e2 < EE; ++e2) { mu[e2] = stats[2 * EE + e2]; rs[e2] = stats[3 * EE + e2]; }

    const int wv = threadIdx.x >> 6;
    const int lane = threadIdx.x & 63;
    const int pr = threadIdx.x >> 1;
    const int hf = threadIdx.x & 1;
    const int pi = pr / EE, pj = pr % EE;
    float acc[8] = {0.f,0.f,0.f,0.f,0.f,0.f,0.f,0.f};
    __syncthreads();

    #pragma unroll 1
    for (int b = blockIdx.x; b < NBATCH; b += gridDim.x) {
        const int pix = b * 64 + lane;
        const bool valid = pix < HWP;
        float lw[CC], lb[CC];
        #pragma unroll
        for (int ch = 0; ch < CC; ++ch) {
            lw[ch] = valid ? ln_w[(size_t)ch * HWP + pix] : 0.f;
            lb[ch] = valid ? ln_b[(size_t)ch * HWP + pix] : 0.f;
        }
        #pragma unroll 1
        for (int g = 0; g < 5; ++g) {
            unsigned int xr[2][16];
            #pragma unroll
            for (int eg = 0; eg < 2; ++eg) {
                const int e2 = g * 2 + eg;
                if (valid) {
                    const uint4* xp = (const uint4*)(x + ((size_t)e2 * HWP + pix) * CC);
                    uint4 a0 = xp[0], a1 = xp[1], a2 = xp[2], a3 = xp[3];
                    xr[eg][0]=a0.x; xr[eg][1]=a0.y; xr[eg][2]=a0.z; xr[eg][3]=a0.w;
                    xr[eg][4]=a1.x; xr[eg][5]=a1.y; xr[eg][6]=a1.z; xr[eg][7]=a1.w;
                    xr[eg][8]=a2.x; xr[eg][9]=a2.y; xr[eg][10]=a2.z; xr[eg][11]=a2.w;
                    xr[eg][12]=a3.x; xr[eg][13]=a3.y; xr[eg][14]=a3.z; xr[eg][15]=a3.w;
                } else {
                    #pragma unroll
                    for (int k2 = 0; k2 < 16; ++k2) xr[eg][k2] = 0u;
                }
            }
            float ka[2][4], qa[2][4];
            #pragma unroll
            for (int eg = 0; eg < 2; ++eg)
                #pragma unroll
                for (int u = 0; u < 4; ++u) { ka[eg][u] = 0.f; qa[eg][u] = 0.f; }
            #pragma unroll
            for (int ch = 0; ch < CC; ++ch) {
                const float4 wk4 = *(const float4*)&wksT[ch * HD + wv * 4];
                const float4 wq4 = *(const float4*)&wqsT[ch * HD + wv * 4];
                #pragma unroll
                for (int eg = 0; eg < 2; ++eg) {
                    const int e2 = g * 2 + eg;
                    unsigned int u = xr[eg][ch >> 1];
                    float xv = (ch & 1) ? bfhi(u) : bflo(u);
                    float lnv = fmaf((xv - mu[e2]) * rs[e2], lw[ch], lb[ch]);
                    ka[eg][0] = fmaf(wk4.x, lnv, ka[eg][0]);
                    ka[eg][1] = fmaf(wk4.y, lnv, ka[eg][1]);
                    ka[eg][2] = fmaf(wk4.z, lnv, ka[eg][2]);
                    ka[eg][3] = fmaf(wk4.w, lnv, ka[eg][3]);
                    qa[eg][0] = fmaf(wq4.x, lnv, qa[eg][0]);
                    qa[eg][1] = fmaf(wq4.y, lnv, qa[eg][1]);
                    qa[eg][2] = fmaf(wq4.z, lnv, qa[eg][2]);
                    qa[eg][3] = fmaf(wq4.w, lnv, qa[eg][3]);
                }
            }
            #pragma unroll
            for (int eg = 0; eg < 2; ++eg) {
                const int e2 = g * 2 + eg;
                uint2 kp, qp;
                kp.x = f2bf(fmaxf(ka[eg][0], 0.f)) | (f2bf(fmaxf(ka[eg][1], 0.f)) << 16);
                kp.y = f2bf(fmaxf(ka[eg][2], 0.f)) | (f2bf(fmaxf(ka[eg][3], 0.f)) << 16);
                qp.x = f2bf(fmaxf(qa[eg][0], 0.f)) | (f2bf(fmaxf(qa[eg][1], 0.f)) << 16);
                qp.y = f2bf(fmaxf(qa[eg][2], 0.f)) | (f2bf(fmaxf(qa[eg][3], 0.f)) << 16);
                *(uint2*)&stage[lane][e2 * 8 + wv * 2] = kp;
                *(uint2*)&stage[lane][80 + e2 * 8 + wv * 2] = qp;
            }
        }
        __syncthreads();
        if (pr < 100) {
            #pragma unroll 8
            for (int p = 0; p < 64; ++p) {
                uint4 kk = *(const uint4*)&stage[p][pi * 8 + hf * 4];
                uint4 qq = *(const uint4*)&stage[p][80 + pj * 8 + hf * 4];
                acc[0] = fmaf(bflo(kk.x), bflo(qq.x), acc[0]);
                acc[1] = fmaf(bfhi(kk.x), bfhi(qq.x), acc[1]);
                acc[2] = fmaf(bflo(kk.y), bflo(qq.y), acc[2]);
                acc[3] = fmaf(bfhi(kk.y), bfhi(qq.y), acc[3]);
                acc[4] = fmaf(bflo(kk.z), bflo(qq.z), acc[4]);
                acc[5] = fmaf(bfhi(kk.z), bfhi(qq.z), acc[5]);
                acc[6] = fmaf(bflo(kk.w), bflo(qq.w), acc[6]);
                acc[7] = fmaf(bfhi(kk.w), bfhi(qq.w), acc[7]);
            }
        }
        __syncthreads();
    }
    if (pr < 100) {
        #pragma unroll
        for (int c2 = 0; c2 < 8; ++c2)
            atomicAdd(&sacc[((hf * 8 + c2) * EE + pi) * EE + pj], acc[c2]);
    }
}

// ---------------- softmax over i + fold A = delta + w - 1/E ----------------
__global__ void softmax_kernel(const float* __restrict__ sacc, float* __restrict__ A)
{
    int t = threadIdx.x;
    if (t >= HD * EE) return;
    int c = t / EE, j = t - c * EE;
    const float norm = (float)(1.0 / 509.8234988357398);  // 1/sqrt(361*720)
    float sv[EE];
    float mx = -1e30f;
    #pragma unroll
    for (int i = 0; i < EE; ++i) { sv[i] = sacc[(c * EE + i) * EE + j] * norm; mx = fmaxf(mx, sv[i]); }
    float sum = 0.f;
    #pragma unroll
    for (int i = 0; i < EE; ++i) { sv[i] = expf(sv[i] - mx); sum += sv[i]; }
    float inv = 1.f / sum;
    #pragma unroll
    for (int i = 0; i < EE; ++i) {
        float wgt = sv[i] * inv;
        A[(c * EE + i) * EE + j] = wgt - (1.f / (float)EE) + (i == j ? 1.f : 0.f);
    }
}

// ---------------- fused: v -> tv (via A) -> out proj + residual + relu -> y ----------------
__global__ __launch_bounds__(256) void final_kernel(
    const unsigned short* __restrict__ x, const float* __restrict__ ln_w,
    const float* __restrict__ ln_b, const float* __restrict__ wvw,
    const float* __restrict__ wo, const float* __restrict__ bo,
    const float* __restrict__ w_out, const float* __restrict__ b_out,
    const float* __restrict__ stats, const float* __restrict__ A,
    float* __restrict__ y)
{
    __shared__ unsigned int vst[128][84];   // 43 KB, bf16-packed v
    __shared__ float As[HD * EE * EE];      // [c][i][j]
    __shared__ float wvsT[CC * HD];         // [ch][c]
    __shared__ float wos[HD * CC];          // [c][ch] (transposed wo)
    __shared__ float bos[CC];
    __shared__ float wouts[CC];
    const int tid = threadIdx.x;
    for (int t = tid; t < CC * HD; t += 256) {
        int ch = t >> 4, c = t & 15;
        wvsT[t] = wvw[c * CC + ch];
        wos[c * CC + ch] = wo[ch * HD + c];
    }
    for (int t = tid; t < HD * EE * EE; t += 256) As[t] = A[t];
    if (tid < CC) { bos[tid] = bo[tid]; wouts[tid] = w_out[tid]; }
    __syncthreads();

    const int wvi = tid >> 6, lane = tid & 63;
    const int lpx = lane & 31, hf = lane >> 5;
    const int mypx = wvi * 32 + lpx;
    const int pix = blockIdx.x * 128 + mypx;
    const bool valid = pix < HWP;

    float mu[EE], rs[EE];
    #pragma unroll
    for (int e2 = 0; e2 < EE; ++e2) { mu[e2] = stats[2 * EE + e2]; rs[e2] = stats[3 * EE + e2]; }

    {
        float lw[CC], lb[CC];
        #pragma unroll
        for (int ch = 0; ch < CC; ++ch) {
            lw[ch] = valid ? ln_w[(size_t)ch * HWP + pix] : 0.f;
            lb[ch] = valid ? ln_b[(size_t)ch * HWP + pix] : 0.f;
        }
        float cb0[8], cb1[8];
        #pragma unroll
        for (int cc = 0; cc < 8; ++cc) { cb0[cc] = 0.f; cb1[cc] = 0.f; }
        #pragma unroll
        for (int ch = 0; ch < CC; ++ch) {
            const float4 w0 = *(const float4*)&wvsT[ch * HD + hf * 8];
            const float4 w1 = *(const float4*)&wvsT[ch * HD + hf * 8 + 4];
            cb1[0] = fmaf(w0.x, lw[ch], cb1[0]); cb1[1] = fmaf(w0.y, lw[ch], cb1[1]);
            cb1[2] = fmaf(w0.z, lw[ch], cb1[2]); cb1[3] = fmaf(w0.w, lw[ch], cb1[3]);
            cb1[4] = fmaf(w1.x, lw[ch], cb1[4]); cb1[5] = fmaf(w1.y, lw[ch], cb1[5]);
            cb1[6] = fmaf(w1.z, lw[ch], cb1[6]); cb1[7] = fmaf(w1.w, lw[ch], cb1[7]);
            cb0[0] = fmaf(w0.x, lb[ch], cb0[0]); cb0[1] = fmaf(w0.y, lb[ch], cb0[1]);
            cb0[2] = fmaf(w0.z, lb[ch], cb0[2]); cb0[3] = fmaf(w0.w, lb[ch], cb0[3]);
            cb0[4] = fmaf(w1.x, lb[ch], cb0[4]); cb0[5] = fmaf(w1.y, lb[ch], cb0[5]);
            cb0[6] = fmaf(w1.z, lb[ch], cb0[6]); cb0[7] = fmaf(w1.w, lb[ch], cb0[7]);
        }
        #pragma unroll 1
        for (int g = 0; g < 5; ++g) {
            unsigned int xr[2][16];
            #pragma unroll
            for (int eg = 0; eg < 2; ++eg) {
                const int e2 = g * 2 + eg;
                if (valid) {
                    const uint4* xp = (const uint4*)(x + ((size_t)e2 * HWP + pix) * CC);
                    uint4 a0 = xp[0], a1 = xp[1], a2 = xp[2], a3 = xp[3];
                    xr[eg][0]=a0.x; xr[eg][1]=a0.y; xr[eg][2]=a0.z; xr[eg][3]=a0.w;
                    xr[eg][4]=a1.x; xr[eg][5]=a1.y; xr[eg][6]=a1.z; xr[eg][7]=a1.w;
                    xr[eg][8]=a2.x; xr[eg][9]=a2.y; xr[eg][10]=a2.z; xr[eg][11]=a2.w;
                    xr[eg][12]=a3.x; xr[eg][13]=a3.y; xr[eg][14]=a3.z; xr[eg][15]=a3.w;
                } else {
                    #pragma unroll
                    for (int k2 = 0; k2 < 16; ++k2) xr[eg][k2] = 0u;
                }
            }
            float a[2][8];
            #pragma unroll
            for (int eg = 0; eg < 2; ++eg)
                #pragma unroll
                for (int cc = 0; cc < 8; ++cc) a[eg][cc] = 0.f;
            #pragma unroll
            for (int ch = 0; ch < CC; ++ch) {
                const float lwc = lw[ch];
                const float4 w0 = *(const float4*)&wvsT[ch * HD + hf * 8];
                const float4 w1 = *(const float4*)&wvsT[ch * HD + hf * 8 + 4];
                #pragma unroll
                for (int eg = 0; eg < 2; ++eg) {
                    unsigned int u = xr[eg][ch >> 1];
                    float t2 = ((ch & 1) ? bfhi(u) : bflo(u)) * lwc;
                    a[eg][0] = fmaf(w0.x, t2, a[eg][0]); a[eg][1] = fmaf(w0.y, t2, a[eg][1]);
                    a[eg][2] = fmaf(w0.z, t2, a[eg][2]); a[eg][3] = fmaf(w0.w, t2, a[eg][3]);
                    a[eg][4] = fmaf(w1.x, t2, a[eg][4]); a[eg][5] = fmaf(w1.y, t2, a[eg][5]);
                    a[eg][6] = fmaf(w1.z, t2, a[eg][6]); a[eg][7] = fmaf(w1.w, t2, a[eg][7]);
                }
            }
            #pragma unroll
            for (int eg = 0; eg < 2; ++eg) {
                const int e2 = g * 2 + eg;
                unsigned int vp[4];
                #pragma unroll
                for (int cc = 0; cc < 8; cc += 2) {
                    float v0 = rs[e2] * a[eg][cc]     - mu[e2] * rs[e2] * cb1[cc]     + cb0[cc];
                    float v1 = rs[e2] * a[eg][cc + 1] - mu[e2] * rs[e2] * cb1[cc + 1] + cb0[cc + 1];
                    vp[cc >> 1] = f2bf(v0) | (f2bf(v1) << 16);
                }
                *(uint4*)&vst[mypx][e2 * 8 + hf * 4] = make_uint4(vp[0], vp[1], vp[2], vp[3]);
            }
        }
    }
    __syncthreads();

    const float boutv = b_out[0];
    #pragma unroll 1
    for (int j = 0; j < EE; ++j) {
        float ar[EE][8];
        #pragma unroll
        for (int i = 0; i < EE; ++i)
            #pragma unroll
            for (int cc = 0; cc < 8; ++cc)
                ar[i][cc] = As[((hf * 8 + cc) * EE + i) * EE + j];
        float tv[8];
        #pragma unroll
        for (int cc = 0; cc < 8; ++cc) tv[cc] = 0.f;
        #pragma unroll
        for (int i = 0; i < EE; ++i) {
            uint4 vv = *(const uint4*)&vst[mypx][i * 8 + hf * 4];
            tv[0] = fmaf(bflo(vv.x), ar[i][0], tv[0]);
            tv[1] = fmaf(bfhi(vv.x), ar[i][1], tv[1]);
            tv[2] = fmaf(bflo(vv.y), ar[i][2], tv[2]);
            tv[3] = fmaf(bfhi(vv.y), ar[i][3], tv[3]);
            tv[4] = fmaf(bflo(vv.z), ar[i][4], tv[4]);
            tv[5] = fmaf(bfhi(vv.z), ar[i][5], tv[5]);
            tv[6] = fmaf(bflo(vv.w), ar[i][6], tv[6]);
            tv[7] = fmaf(bfhi(vv.w), ar[i][7], tv[7]);
        }
        unsigned int xj[16];
        if (valid) {
            const uint4* xp = (const uint4*)(x + ((size_t)j * HWP + pix) * CC);
            uint4 a0 = xp[0], a1 = xp[1], a2 = xp[2], a3 = xp[3];
            xj[0]=a0.x; xj[1]=a0.y; xj[2]=a0.z; xj[3]=a0.w;
            xj[4]=a1.x; xj[5]=a1.y; xj[6]=a1.z; xj[7]=a1.w;
            xj[8]=a2.x; xj[9]=a2.y; xj[10]=a2.z; xj[11]=a2.w;
            xj[12]=a3.x; xj[13]=a3.y; xj[14]=a3.z; xj[15]=a3.w;
        } else {
            #pragma unroll
            for (int k2 = 0; k2 < 16; ++k2) xj[k2] = 0u;
        }
        float o[CC];
        #pragma unroll
        for (int ch = 0; ch < CC; ++ch) {
            unsigned int u = xj[ch >> 1];
            float xv = (ch & 1) ? bfhi(u) : bflo(u);
            o[ch] = hf ? 0.f : (bos[ch] + xv);
        }
        #pragma unroll
        for (int cc = 0; cc < 8; ++cc) {
            const float tvc = tv[cc];
            const float* wcol = &wos[(hf * 8 + cc) * CC];
            #pragma unroll
            for (int ch = 0; ch < CC; ++ch) o[ch] = fmaf(wcol[ch], tvc, o[ch]);
        }
        float yv = 0.f;
        #pragma unroll
        for (int ch = 0; ch < CC; ++ch) {
            float of = o[ch] + __shfl_xor(o[ch], 32);
            if ((ch >> 4) == hf) yv = fmaf(wouts[ch], fmaxf(of, 0.f), yv);
        }
        yv += __shfl_xor(yv, 32);
        if (hf == 0 && valid) y[(size_t)j * HWP + pix] = yv + boutv;
    }
}

extern "C" void kernel_launch(void* const* d_in, const int* in_sizes, int n_in,
                              void* d_out, int out_size, void* d_ws, size_t ws_size,
                              hipStream_t stream)
{
    const float* inp   = (const float*)d_in[0];
    const float* emb_w = (const float*)d_in[1];
    const float* emb_b = (const float*)d_in[2];
    const float* ln_w  = (const float*)d_in[3];
    const float* ln_b  = (const float*)d_in[4];
    const float* wv    = (const float*)d_in[5];
    const float* wk    = (const float*)d_in[6];
    const float* wq    = (const float*)d_in[7];
    const float* wo    = (const float*)d_in[8];
    const float* bo    = (const float*)d_in[9];
    const float* w_out = (const float*)d_in[10];
    const float* b_out = (const float*)d_in[11];
    float* y = (float*)d_out;

    // ws: x bf16 channel-last [E][HW][32] = 166,348,800 B; then stats(40)+sacc(1600)+A(1600)
    unsigned short* xbuf = (unsigned short*)d_ws;
    float* stats = (float*)((char*)d_ws + (size_t)EE * HWP * CC * 2);
    float* sacc  = stats + 40;
    float* Amat  = sacc + HD * EE * EE;

    zero_kernel<<<7, 256, 0, stream>>>(stats);
    conv_selu_kernel<<<dim3(12, 23, EE * 2), dim3(64, 4), 0, stream>>>(inp, emb_w, emb_b, xbuf, stats);
    ln_stats_kernel<<<1, 64, 0, stream>>>(stats);
    scores_fused_kernel<<<1024, 256, 0, stream>>>(xbuf, ln_w, ln_b, wk, wq, stats, sacc);
    softmax_kernel<<<1, 192, 0, stream>>>(sacc, Amat);
    final_kernel<<<(HWP + 127) / 128, 256, 0, stream>>>(xbuf, ln_w, ln_b, wv, wo, bo,
                                                        w_out, b_out, stats, Amat, y);
}

// Round 11
// 1328.280 us; speedup vs baseline: 1.2117x; 1.2117x over previous
//
#include <hip/hip_runtime.h>
#include <hip/hip_bf16.h>

#define HH 361
#define WW 720
#define HWP (HH*WW)          // 259920
#define CIN 11
#define CC 32
#define HD 16
#define EE 10
#define NBATCH ((HWP + 63) / 64)   // 4062
#define LN_EPS 1e-5f
#define SELU_ALPHA 1.6732632423543772f
#define SELU_SCALE 1.0507009873554805f
#define SELU_SA (SELU_SCALE * SELU_ALPHA)

// bf16 helpers (round-to-nearest-even pack; cheap unpacks from packed dwords)
static __device__ __forceinline__ unsigned int f2bf(float f) {
    unsigned int u = __float_as_uint(f);
    return (u + 0x7FFFu + ((u >> 16) & 1u)) >> 16;
}
static __device__ __forceinline__ float bflo(unsigned int u) {
    return __uint_as_float(u << 16);
}
static __device__ __forceinline__ float bfhi(unsigned int u) {
    return __uint_as_float(u & 0xffff0000u);
}
static __device__ __forceinline__ float selu_f(float v) {
    // fast SELU via v_exp_f32; abs err <= ~2e-6, invisible vs bf16 storage
    return v > 0.f ? SELU_SCALE * v : SELU_SA * (__expf(v) - 1.f);
}

// ---------------- zero accumulators ----------------
__global__ void zero_kernel(float* __restrict__ p) {
    int t = blockIdx.x * 256 + threadIdx.x;
    if (t < 40 + HD * EE * EE) p[t] = 0.f;
}

// ---------------- conv: INTERIOR blocks (x 1..10, y 1..21), guard-free ----------------
// grid (10, 21, 20), block (64,4). z = e*2 + half. Thread = 1 col x 4 rows x 16 ch.
// No lat-guards, no lon-wrap: per row one float4 + one scalar off a single base ptr.
// launch_bounds(256,4) pins VGPR <= 128 (occupancy bucket boundary -- r10 lesson).
__global__ __launch_bounds__(256, 4) void conv_int_kernel(
    const float* __restrict__ inp, const float* __restrict__ emb_w,
    const float* __restrict__ emb_b, unsigned short* __restrict__ xout,
    float* __restrict__ stats)
{
    __shared__ float wlds[CIN * 25 * 16];   // 17.6 KB
    __shared__ float bsm[16];
    __shared__ float red[8];
    const int z = blockIdx.z;
    const int e = z >> 1, half = z & 1;
    const int tid = threadIdx.y * 64 + threadIdx.x;
    for (int t = tid; t < CIN * 25 * 16; t += 256) {
        int u = t & 15; int rest = t >> 4; int k25 = rest % 25; int ci = rest / 25;
        wlds[t] = emb_w[((half * 16 + u) * CIN + ci) * 25 + k25];
    }
    if (tid < 16) bsm[tid] = emb_b[half * 16 + tid];
    __syncthreads();

    const int w  = (blockIdx.x + 1) * 64 + threadIdx.x;    // 64..703
    const int h0 = (blockIdx.y + 1) * 16 + threadIdx.y * 4; // 16..348; halo 14..353 in-range

    float acc[4][16];
    #pragma unroll
    for (int hs = 0; hs < 4; ++hs)
        #pragma unroll
        for (int c = 0; c < 16; ++c) acc[hs][c] = bsm[c];

    #pragma unroll 1
    for (int ci = 0; ci < CIN; ++ci) {
        const float* rp2 = inp + ((size_t)(e * CIN + ci)) * HWP + (size_t)(h0 - 2) * WW + (w - 2);
        float in[8][5];
        #pragma unroll
        for (int r = 0; r < 8; ++r) {
            float4 q = *(const float4*)rp2;
            in[r][0] = q.x; in[r][1] = q.y; in[r][2] = q.z; in[r][3] = q.w;
            in[r][4] = rp2[4];
            rp2 += WW;
        }
        #pragma unroll
        for (int kh = 0; kh < 5; ++kh) {
            #pragma unroll
            for (int kw = 0; kw < 5; ++kw) {
                const float* wp = &wlds[(ci * 25 + kh * 5 + kw) * 16];
                const float4 w0 = *(const float4*)(wp);
                const float4 w1 = *(const float4*)(wp + 4);
                const float4 w2 = *(const float4*)(wp + 8);
                const float4 w3 = *(const float4*)(wp + 12);
                #pragma unroll
                for (int hs = 0; hs < 4; ++hs) {
                    const float iv = in[hs + kh][kw];
                    acc[hs][0]  = fmaf(iv, w0.x, acc[hs][0]);
                    acc[hs][1]  = fmaf(iv, w0.y, acc[hs][1]);
                    acc[hs][2]  = fmaf(iv, w0.z, acc[hs][2]);
                    acc[hs][3]  = fmaf(iv, w0.w, acc[hs][3]);
                    acc[hs][4]  = fmaf(iv, w1.x, acc[hs][4]);
                    acc[hs][5]  = fmaf(iv, w1.y, acc[hs][5]);
                    acc[hs][6]  = fmaf(iv, w1.z, acc[hs][6]);
                    acc[hs][7]  = fmaf(iv, w1.w, acc[hs][7]);
                    acc[hs][8]  = fmaf(iv, w2.x, acc[hs][8]);
                    acc[hs][9]  = fmaf(iv, w2.y, acc[hs][9]);
                    acc[hs][10] = fmaf(iv, w2.z, acc[hs][10]);
                    acc[hs][11] = fmaf(iv, w2.w, acc[hs][11]);
                    acc[hs][12] = fmaf(iv, w3.x, acc[hs][12]);
                    acc[hs][13] = fmaf(iv, w3.y, acc[hs][13]);
                    acc[hs][14] = fmaf(iv, w3.z, acc[hs][14]);
                    acc[hs][15] = fmaf(iv, w3.w, acc[hs][15]);
                }
            }
        }
    }

    float s = 0.f, s2 = 0.f;
    #pragma unroll
    for (int hs = 0; hs < 4; ++hs) {
        const int h = h0 + hs;   // always < HH
        unsigned int pk[8];
        #pragma unroll
        for (int c = 0; c < 16; c += 2) {
            float v0 = selu_f(acc[hs][c]);
            float v1 = selu_f(acc[hs][c + 1]);
            s += v0 + v1; s2 = fmaf(v0, v0, s2); s2 = fmaf(v1, v1, s2);
            pk[c >> 1] = f2bf(v0) | (f2bf(v1) << 16);
        }
        uint4* dst = (uint4*)(xout + ((size_t)e * HWP + (size_t)h * WW + w) * CC + half * 16);
        dst[0] = make_uint4(pk[0], pk[1], pk[2], pk[3]);
        dst[1] = make_uint4(pk[4], pk[5], pk[6], pk[7]);
    }
    #pragma unroll
    for (int off = 32; off; off >>= 1) { s += __shfl_down(s, off); s2 += __shfl_down(s2, off); }
    if ((tid & 63) == 0) { red[tid >> 6] = s; red[4 + (tid >> 6)] = s2; }
    __syncthreads();
    if (tid == 0) {
        atomicAdd(&stats[e], red[0] + red[1] + red[2] + red[3]);
        atomicAdd(&stats[EE + e], red[4] + red[5] + red[6] + red[7]);
    }
}

// ---------------- conv: BOUNDARY blocks (frame), guarded r9 path ----------------
// grid (66, 20), block (64,4). blockIdx.y = e*2 + half.
// b<23: bx=0,by=b ; b<46: bx=11,by=b-23 ; b<56: bx=b-45,by=0 ; else bx=b-55,by=22.
__global__ __launch_bounds__(256) void conv_bnd_kernel(
    const float* __restrict__ inp, const float* __restrict__ emb_w,
    const float* __restrict__ emb_b, unsigned short* __restrict__ xout,
    float* __restrict__ stats)
{
    __shared__ float wlds[CIN * 25 * 16];
    __shared__ float bsm[16];
    __shared__ float red[8];
    const int z = blockIdx.y;
    const int e = z >> 1, half = z & 1;
    const int tid = threadIdx.y * 64 + threadIdx.x;
    for (int t = tid; t < CIN * 25 * 16; t += 256) {
        int u = t & 15; int rest = t >> 4; int k25 = rest % 25; int ci = rest / 25;
        wlds[t] = emb_w[((half * 16 + u) * CIN + ci) * 25 + k25];
    }
    if (tid < 16) bsm[tid] = emb_b[half * 16 + tid];
    __syncthreads();

    const int b = blockIdx.x;
    int bx, by;
    if (b < 23)      { bx = 0;      by = b; }
    else if (b < 46) { bx = 11;     by = b - 23; }
    else if (b < 56) { bx = b - 45; by = 0; }
    else             { bx = b - 55; by = 22; }

    const int w  = bx * 64 + threadIdx.x;
    const int h0 = by * 16 + threadIdx.y * 4;
    const bool active = (w < WW);

    int wl[5];
    if (active) {
        #pragma unroll
        for (int d = 0; d < 5; ++d) {
            int ww = w + d - 2; if (ww < 0) ww += WW; if (ww >= WW) ww -= WW; wl[d] = ww;
        }
    }

    float acc[4][16];
    #pragma unroll
    for (int hs = 0; hs < 4; ++hs)
        #pragma unroll
        for (int c = 0; c < 16; ++c) acc[hs][c] = bsm[c];

    if (active) {
        #pragma unroll 1
        for (int ci = 0; ci < CIN; ++ci) {
            const float* ip = inp + ((size_t)(e * CIN + ci)) * HWP;
            float in[8][5];
            #pragma unroll
            for (int r = 0; r < 8; ++r) {
                int hh = h0 + r - 2;
                bool v = (hh >= 0 && hh < HH);
                const float* rp = ip + (size_t)hh * WW;
                #pragma unroll
                for (int d = 0; d < 5; ++d) in[r][d] = v ? rp[wl[d]] : 0.f;
            }
            #pragma unroll
            for (int kh = 0; kh < 5; ++kh) {
                #pragma unroll
                for (int kw = 0; kw < 5; ++kw) {
                    const float* wp = &wlds[(ci * 25 + kh * 5 + kw) * 16];
                    const float4 w0 = *(const float4*)(wp);
                    const float4 w1 = *(const float4*)(wp + 4);
                    const float4 w2 = *(const float4*)(wp + 8);
                    const float4 w3 = *(const float4*)(wp + 12);
                    #pragma unroll
                    for (int hs = 0; hs < 4; ++hs) {
                        const float iv = in[hs + kh][kw];
                        acc[hs][0]  = fmaf(iv, w0.x, acc[hs][0]);
                        acc[hs][1]  = fmaf(iv, w0.y, acc[hs][1]);
                        acc[hs][2]  = fmaf(iv, w0.z, acc[hs][2]);
                        acc[hs][3]  = fmaf(iv, w0.w, acc[hs][3]);
                        acc[hs][4]  = fmaf(iv, w1.x, acc[hs][4]);
                        acc[hs][5]  = fmaf(iv, w1.y, acc[hs][5]);
                        acc[hs][6]  = fmaf(iv, w1.z, acc[hs][6]);
                        acc[hs][7]  = fmaf(iv, w1.w, acc[hs][7]);
                        acc[hs][8]  = fmaf(iv, w2.x, acc[hs][8]);
                        acc[hs][9]  = fmaf(iv, w2.y, acc[hs][9]);
                        acc[hs][10] = fmaf(iv, w2.z, acc[hs][10]);
                        acc[hs][11] = fmaf(iv, w2.w, acc[hs][11]);
                        acc[hs][12] = fmaf(iv, w3.x, acc[hs][12]);
                        acc[hs][13] = fmaf(iv, w3.y, acc[hs][13]);
                        acc[hs][14] = fmaf(iv, w3.z, acc[hs][14]);
                        acc[hs][15] = fmaf(iv, w3.w, acc[hs][15]);
                    }
                }
            }
        }
    }

    float s = 0.f, s2 = 0.f;
    #pragma unroll
    for (int hs = 0; hs < 4; ++hs) {
        const int h = h0 + hs;
        if (active && h < HH) {
            unsigned int pk[8];
            #pragma unroll
            for (int c = 0; c < 16; c += 2) {
                float v0 = selu_f(acc[hs][c]);
                float v1 = selu_f(acc[hs][c + 1]);
                s += v0 + v1; s2 = fmaf(v0, v0, s2); s2 = fmaf(v1, v1, s2);
                pk[c >> 1] = f2bf(v0) | (f2bf(v1) << 16);
            }
            uint4* dst = (uint4*)(xout + ((size_t)e * HWP + (size_t)h * WW + w) * CC + half * 16);
            dst[0] = make_uint4(pk[0], pk[1], pk[2], pk[3]);
            dst[1] = make_uint4(pk[4], pk[5], pk[6], pk[7]);
        }
    }
    #pragma unroll
    for (int off = 32; off; off >>= 1) { s += __shfl_down(s, off); s2 += __shfl_down(s2, off); }
    if ((tid & 63) == 0) { red[tid >> 6] = s; red[4 + (tid >> 6)] = s2; }
    __syncthreads();
    if (tid == 0) {
        atomicAdd(&stats[e], red[0] + red[1] + red[2] + red[3]);
        atomicAdd(&stats[EE + e], red[4] + red[5] + red[6] + red[7]);
    }
}

// ---------------- finalize LN stats ----------------
__global__ void ln_stats_kernel(float* __restrict__ stats) {
    int e = threadIdx.x;
    if (e < EE) {
        const float N = (float)CC * (float)HWP;
        float mu = stats[e] / N;
        float var = stats[EE + e] / N - mu * mu;
        stats[2 * EE + e] = mu;
        stats[3 * EE + e] = rsqrtf(var + LN_EPS);
    }
}

// ---------------- fused k,q + scores ----------------
__global__ __launch_bounds__(256) void scores_fused_kernel(
    const unsigned short* __restrict__ x, const float* __restrict__ ln_w,
    const float* __restrict__ ln_b, const float* __restrict__ wk,
    const float* __restrict__ wq, const float* __restrict__ stats,
    float* __restrict__ sacc)
{
    __shared__ float wksT[CC * HD], wqsT[CC * HD];   // [ch][c]
    __shared__ unsigned int stage[64][164];          // k at [e*8+d], q at [80+e*8+d]
    for (int t = threadIdx.x; t < CC * HD; t += 256) {
        int ch = t >> 4, c = t & 15;
        wksT[t] = wk[c * CC + ch];
        wqsT[t] = wq[c * CC + ch];
    }
    float mu[EE], rs[EE];
    #pragma unroll
    for (int e2 = 0; e2 < EE; ++e2) { mu[e2] = stats[2 * EE + e2]; rs[e2] = stats[3 * EE + e2]; }

    const int wv = threadIdx.x >> 6;
    const int lane = threadIdx.x & 63;
    const int pr = threadIdx.x >> 1;
    const int hf = threadIdx.x & 1;
    const int pi = pr / EE, pj = pr % EE;
    float acc[8] = {0.f,0.f,0.f,0.f,0.f,0.f,0.f,0.f};
    __syncthreads();

    #pragma unroll 1
    for (int b = blockIdx.x; b < NBATCH; b += gridDim.x) {
        const int pix = b * 64 + lane;
        const bool valid = pix < HWP;
        float lw[CC], lb[CC];
        #pragma unroll
        for (int ch = 0; ch < CC; ++ch) {
            lw[ch] = valid ? ln_w[(size_t)ch * HWP + pix] : 0.f;
            lb[ch] = valid ? ln_b[(size_t)ch * HWP + pix] : 0.f;
        }
        #pragma unroll 1
        for (int g = 0; g < 5; ++g) {
            unsigned int xr[2][16];
            #pragma unroll
            for (int eg = 0; eg < 2; ++eg) {
                const int e2 = g * 2 + eg;
                if (valid) {
                    const uint4* xp = (const uint4*)(x + ((size_t)e2 * HWP + pix) * CC);
                    uint4 a0 = xp[0], a1 = xp[1], a2 = xp[2], a3 = xp[3];
                    xr[eg][0]=a0.x; xr[eg][1]=a0.y; xr[eg][2]=a0.z; xr[eg][3]=a0.w;
                    xr[eg][4]=a1.x; xr[eg][5]=a1.y; xr[eg][6]=a1.z; xr[eg][7]=a1.w;
                    xr[eg][8]=a2.x; xr[eg][9]=a2.y; xr[eg][10]=a2.z; xr[eg][11]=a2.w;
                    xr[eg][12]=a3.x; xr[eg][13]=a3.y; xr[eg][14]=a3.z; xr[eg][15]=a3.w;
                } else {
                    #pragma unroll
                    for (int k2 = 0; k2 < 16; ++k2) xr[eg][k2] = 0u;
                }
            }
            float ka[2][4], qa[2][4];
            #pragma unroll
            for (int eg = 0; eg < 2; ++eg)
                #pragma unroll
                for (int u = 0; u < 4; ++u) { ka[eg][u] = 0.f; qa[eg][u] = 0.f; }
            #pragma unroll
            for (int ch = 0; ch < CC; ++ch) {
                const float4 wk4 = *(const float4*)&wksT[ch * HD + wv * 4];
                const float4 wq4 = *(const float4*)&wqsT[ch * HD + wv * 4];
                #pragma unroll
                for (int eg = 0; eg < 2; ++eg) {
                    const int e2 = g * 2 + eg;
                    unsigned int u = xr[eg][ch >> 1];
                    float xv = (ch & 1) ? bfhi(u) : bflo(u);
                    float lnv = fmaf((xv - mu[e2]) * rs[e2], lw[ch], lb[ch]);
                    ka[eg][0] = fmaf(wk4.x, lnv, ka[eg][0]);
                    ka[eg][1] = fmaf(wk4.y, lnv, ka[eg][1]);
                    ka[eg][2] = fmaf(wk4.z, lnv, ka[eg][2]);
                    ka[eg][3] = fmaf(wk4.w, lnv, ka[eg][3]);
                    qa[eg][0] = fmaf(wq4.x, lnv, qa[eg][0]);
                    qa[eg][1] = fmaf(wq4.y, lnv, qa[eg][1]);
                    qa[eg][2] = fmaf(wq4.z, lnv, qa[eg][2]);
                    qa[eg][3] = fmaf(wq4.w, lnv, qa[eg][3]);
                }
            }
            #pragma unroll
            for (int eg = 0; eg < 2; ++eg) {
                const int e2 = g * 2 + eg;
                uint2 kp, qp;
                kp.x = f2bf(fmaxf(ka[eg][0], 0.f)) | (f2bf(fmaxf(ka[eg][1], 0.f)) << 16);
                kp.y = f2bf(fmaxf(ka[eg][2], 0.f)) | (f2bf(fmaxf(ka[eg][3], 0.f)) << 16);
                qp.x = f2bf(fmaxf(qa[eg][0], 0.f)) | (f2bf(fmaxf(qa[eg][1], 0.f)) << 16);
                qp.y = f2bf(fmaxf(qa[eg][2], 0.f)) | (f2bf(fmaxf(qa[eg][3], 0.f)) << 16);
                *(uint2*)&stage[lane][e2 * 8 + wv * 2] = kp;
                *(uint2*)&stage[lane][80 + e2 * 8 + wv * 2] = qp;
            }
        }
        __syncthreads();
        if (pr < 100) {
            #pragma unroll 8
            for (int p = 0; p < 64; ++p) {
                uint4 kk = *(const uint4*)&stage[p][pi * 8 + hf * 4];
                uint4 qq = *(const uint4*)&stage[p][80 + pj * 8 + hf * 4];
                acc[0] = fmaf(bflo(kk.x), bflo(qq.x), acc[0]);
                acc[1] = fmaf(bfhi(kk.x), bfhi(qq.x), acc[1]);
                acc[2] = fmaf(bflo(kk.y), bflo(qq.y), acc[2]);
                acc[3] = fmaf(bfhi(kk.y), bfhi(qq.y), acc[3]);
                acc[4] = fmaf(bflo(kk.z), bflo(qq.z), acc[4]);
                acc[5] = fmaf(bfhi(kk.z), bfhi(qq.z), acc[5]);
                acc[6] = fmaf(bflo(kk.w), bflo(qq.w), acc[6]);
                acc[7] = fmaf(bfhi(kk.w), bfhi(qq.w), acc[7]);
            }
        }
        __syncthreads();
    }
    if (pr < 100) {
        #pragma unroll
        for (int c2 = 0; c2 < 8; ++c2)
            atomicAdd(&sacc[((hf * 8 + c2) * EE + pi) * EE + pj], acc[c2]);
    }
}

// ---------------- softmax over i + fold A = delta + w - 1/E ----------------
__global__ void softmax_kernel(const float* __restrict__ sacc, float* __restrict__ A)
{
    int t = threadIdx.x;
    if (t >= HD * EE) return;
    int c = t / EE, j = t - c * EE;
    const float norm = (float)(1.0 / 509.8234988357398);  // 1/sqrt(361*720)
    float sv[EE];
    float mx = -1e30f;
    #pragma unroll
    for (int i = 0; i < EE; ++i) { sv[i] = sacc[(c * EE + i) * EE + j] * norm; mx = fmaxf(mx, sv[i]); }
    float sum = 0.f;
    #pragma unroll
    for (int i = 0; i < EE; ++i) { sv[i] = expf(sv[i] - mx); sum += sv[i]; }
    float inv = 1.f / sum;
    #pragma unroll
    for (int i = 0; i < EE; ++i) {
        float wgt = sv[i] * inv;
        A[(c * EE + i) * EE + j] = wgt - (1.f / (float)EE) + (i == j ? 1.f : 0.f);
    }
}

// ---------------- fused: v -> tv (via A) -> out proj + residual + relu -> y ----------------
__global__ __launch_bounds__(256) void final_kernel(
    const unsigned short* __restrict__ x, const float* __restrict__ ln_w,
    const float* __restrict__ ln_b, const float* __restrict__ wvw,
    const float* __restrict__ wo, const float* __restrict__ bo,
    const float* __restrict__ w_out, const float* __restrict__ b_out,
    const float* __restrict__ stats, const float* __restrict__ A,
    float* __restrict__ y)
{
    __shared__ unsigned int vst[128][84];   // 43 KB, bf16-packed v
    __shared__ float As[HD * EE * EE];      // [c][i][j]
    __shared__ float wvsT[CC * HD];         // [ch][c]
    __shared__ float wos[HD * CC];          // [c][ch] (transposed wo)
    __shared__ float bos[CC];
    __shared__ float wouts[CC];
    const int tid = threadIdx.x;
    for (int t = tid; t < CC * HD; t += 256) {
        int ch = t >> 4, c = t & 15;
        wvsT[t] = wvw[c * CC + ch];
        wos[c * CC + ch] = wo[ch * HD + c];
    }
    for (int t = tid; t < HD * EE * EE; t += 256) As[t] = A[t];
    if (tid < CC) { bos[tid] = bo[tid]; wouts[tid] = w_out[tid]; }
    __syncthreads();

    const int wvi = tid >> 6, lane = tid & 63;
    const int lpx = lane & 31, hf = lane >> 5;
    const int mypx = wvi * 32 + lpx;
    const int pix = blockIdx.x * 128 + mypx;
    const bool valid = pix < HWP;

    float mu[EE], rs[EE];
    #pragma unroll
    for (int e2 = 0; e2 < EE; ++e2) { mu[e2] = stats[2 * EE + e2]; rs[e2] = stats[3 * EE + e2]; }

    {
        float lw[CC], lb[CC];
        #pragma unroll
        for (int ch = 0; ch < CC; ++ch) {
            lw[ch] = valid ? ln_w[(size_t)ch * HWP + pix] : 0.f;
            lb[ch] = valid ? ln_b[(size_t)ch * HWP + pix] : 0.f;
        }
        float cb0[8], cb1[8];
        #pragma unroll
        for (int cc = 0; cc < 8; ++cc) { cb0[cc] = 0.f; cb1[cc] = 0.f; }
        #pragma unroll
        for (int ch = 0; ch < CC; ++ch) {
            const float4 w0 = *(const float4*)&wvsT[ch * HD + hf * 8];
            const float4 w1 = *(const float4*)&wvsT[ch * HD + hf * 8 + 4];
            cb1[0] = fmaf(w0.x, lw[ch], cb1[0]); cb1[1] = fmaf(w0.y, lw[ch], cb1[1]);
            cb1[2] = fmaf(w0.z, lw[ch], cb1[2]); cb1[3] = fmaf(w0.w, lw[ch], cb1[3]);
            cb1[4] = fmaf(w1.x, lw[ch], cb1[4]); cb1[5] = fmaf(w1.y, lw[ch], cb1[5]);
            cb1[6] = fmaf(w1.z, lw[ch], cb1[6]); cb1[7] = fmaf(w1.w, lw[ch], cb1[7]);
            cb0[0] = fmaf(w0.x, lb[ch], cb0[0]); cb0[1] = fmaf(w0.y, lb[ch], cb0[1]);
            cb0[2] = fmaf(w0.z, lb[ch], cb0[2]); cb0[3] = fmaf(w0.w, lb[ch], cb0[3]);
            cb0[4] = fmaf(w1.x, lb[ch], cb0[4]); cb0[5] = fmaf(w1.y, lb[ch], cb0[5]);
            cb0[6] = fmaf(w1.z, lb[ch], cb0[6]); cb0[7] = fmaf(w1.w, lb[ch], cb0[7]);
        }
        #pragma unroll 1
        for (int g = 0; g < 5; ++g) {
            unsigned int xr[2][16];
            #pragma unroll
            for (int eg = 0; eg < 2; ++eg) {
                const int e2 = g * 2 + eg;
                if (valid) {
                    const uint4* xp = (const uint4*)(x + ((size_t)e2 * HWP + pix) * CC);
                    uint4 a0 = xp[0], a1 = xp[1], a2 = xp[2], a3 = xp[3];
                    xr[eg][0]=a0.x; xr[eg][1]=a0.y; xr[eg][2]=a0.z; xr[eg][3]=a0.w;
                    xr[eg][4]=a1.x; xr[eg][5]=a1.y; xr[eg][6]=a1.z; xr[eg][7]=a1.w;
                    xr[eg][8]=a2.x; xr[eg][9]=a2.y; xr[eg][10]=a2.z; xr[eg][11]=a2.w;
                    xr[eg][12]=a3.x; xr[eg][13]=a3.y; xr[eg][14]=a3.z; xr[eg][15]=a3.w;
                } else {
                    #pragma unroll
                    for (int k2 = 0; k2 < 16; ++k2) xr[eg][k2] = 0u;
                }
            }
            float a[2][8];
            #pragma unroll
            for (int eg = 0; eg < 2; ++eg)
                #pragma unroll
                for (int cc = 0; cc < 8; ++cc) a[eg][cc] = 0.f;
            #pragma unroll
            for (int ch = 0; ch < CC; ++ch) {
                const float lwc = lw[ch];
                const float4 w0 = *(const float4*)&wvsT[ch * HD + hf * 8];
                const float4 w1 = *(const float4*)&wvsT[ch * HD + hf * 8 + 4];
                #pragma unroll
                for (int eg = 0; eg < 2; ++eg) {
                    unsigned int u = xr[eg][ch >> 1];
                    float t2 = ((ch & 1) ? bfhi(u) : bflo(u)) * lwc;
                    a[eg][0] = fmaf(w0.x, t2, a[eg][0]); a[eg][1] = fmaf(w0.y, t2, a[eg][1]);
                    a[eg][2] = fmaf(w0.z, t2, a[eg][2]); a[eg][3] = fmaf(w0.w, t2, a[eg][3]);
                    a[eg][4] = fmaf(w1.x, t2, a[eg][4]); a[eg][5] = fmaf(w1.y, t2, a[eg][5]);
                    a[eg][6] = fmaf(w1.z, t2, a[eg][6]); a[eg][7] = fmaf(w1.w, t2, a[eg][7]);
                }
            }
            #pragma unroll
            for (int eg = 0; eg < 2; ++eg) {
                const int e2 = g * 2 + eg;
                unsigned int vp[4];
                #pragma unroll
                for (int cc = 0; cc < 8; cc += 2) {
                    float v0 = rs[e2] * a[eg][cc]     - mu[e2] * rs[e2] * cb1[cc]     + cb0[cc];
                    float v1 = rs[e2] * a[eg][cc + 1] - mu[e2] * rs[e2] * cb1[cc + 1] + cb0[cc + 1];
                    vp[cc >> 1] = f2bf(v0) | (f2bf(v1) << 16);
                }
                *(uint4*)&vst[mypx][e2 * 8 + hf * 4] = make_uint4(vp[0], vp[1], vp[2], vp[3]);
            }
        }
    }
    __syncthreads();

    const float boutv = b_out[0];
    #pragma unroll 1
    for (int j = 0; j < EE; ++j) {
        float ar[EE][8];
        #pragma unroll
        for (int i = 0; i < EE; ++i)
            #pragma unroll
            for (int cc = 0; cc < 8; ++cc)
                ar[i][cc] = As[((hf * 8 + cc) * EE + i) * EE + j];
        float tv[8];
        #pragma unroll
        for (int cc = 0; cc < 8; ++cc) tv[cc] = 0.f;
        #pragma unroll
        for (int i = 0; i < EE; ++i) {
            uint4 vv = *(const uint4*)&vst[mypx][i * 8 + hf * 4];
            tv[0] = fmaf(bflo(vv.x), ar[i][0], tv[0]);
            tv[1] = fmaf(bfhi(vv.x), ar[i][1], tv[1]);
            tv[2] = fmaf(bflo(vv.y), ar[i][2], tv[2]);
            tv[3] = fmaf(bfhi(vv.y), ar[i][3], tv[3]);
            tv[4] = fmaf(bflo(vv.z), ar[i][4], tv[4]);
            tv[5] = fmaf(bfhi(vv.z), ar[i][5], tv[5]);
            tv[6] = fmaf(bflo(vv.w), ar[i][6], tv[6]);
            tv[7] = fmaf(bfhi(vv.w), ar[i][7], tv[7]);
        }
        unsigned int xj[16];
        if (valid) {
            const uint4* xp = (const uint4*)(x + ((size_t)j * HWP + pix) * CC);
            uint4 a0 = xp[0], a1 = xp[1], a2 = xp[2], a3 = xp[3];
            xj[0]=a0.x; xj[1]=a0.y; xj[2]=a0.z; xj[3]=a0.w;
            xj[4]=a1.x; xj[5]=a1.y; xj[6]=a1.z; xj[7]=a1.w;
            xj[8]=a2.x; xj[9]=a2.y; xj[10]=a2.z; xj[11]=a2.w;
            xj[12]=a3.x; xj[13]=a3.y; xj[14]=a3.z; xj[15]=a3.w;
        } else {
            #pragma unroll
            for (int k2 = 0; k2 < 16; ++k2) xj[k2] = 0u;
        }
        float o[CC];
        #pragma unroll
        for (int ch = 0; ch < CC; ++ch) {
            unsigned int u = xj[ch >> 1];
            float xv = (ch & 1) ? bfhi(u) : bflo(u);
            o[ch] = hf ? 0.f : (bos[ch] + xv);
        }
        #pragma unroll
        for (int cc = 0; cc < 8; ++cc) {
            const float tvc = tv[cc];
            const float* wcol = &wos[(hf * 8 + cc) * CC];
            #pragma unroll
            for (int ch = 0; ch < CC; ++ch) o[ch] = fmaf(wcol[ch], tvc, o[ch]);
        }
        float yv = 0.f;
        #pragma unroll
        for (int ch = 0; ch < CC; ++ch) {
            float of = o[ch] + __shfl_xor(o[ch], 32);
            if ((ch >> 4) == hf) yv = fmaf(wouts[ch], fmaxf(of, 0.f), yv);
        }
        yv += __shfl_xor(yv, 32);
        if (hf == 0 && valid) y[(size_t)j * HWP + pix] = yv + boutv;
    }
}

extern "C" void kernel_launch(void* const* d_in, const int* in_sizes, int n_in,
                              void* d_out, int out_size, void* d_ws, size_t ws_size,
                              hipStream_t stream)
{
    const float* inp   = (const float*)d_in[0];
    const float* emb_w = (const float*)d_in[1];
    const float* emb_b = (const float*)d_in[2];
    const float* ln_w  = (const float*)d_in[3];
    const float* ln_b  = (const float*)d_in[4];
    const float* wv    = (const float*)d_in[5];
    const float* wk    = (const float*)d_in[6];
    const float* wq    = (const float*)d_in[7];
    const float* wo    = (const float*)d_in[8];
    const float* bo    = (const float*)d_in[9];
    const float* w_out = (const float*)d_in[10];
    const float* b_out = (const float*)d_in[11];
    float* y = (float*)d_out;

    // ws: x bf16 channel-last [E][HW][32] = 166,348,800 B; then stats(40)+sacc(1600)+A(1600)
    unsigned short* xbuf = (unsigned short*)d_ws;
    float* stats = (float*)((char*)d_ws + (size_t)EE * HWP * CC * 2);
    float* sacc  = stats + 40;
    float* Amat  = sacc + HD * EE * EE;

    zero_kernel<<<7, 256, 0, stream>>>(stats);
    conv_int_kernel<<<dim3(10, 21, EE * 2), dim3(64, 4), 0, stream>>>(inp, emb_w, emb_b, xbuf, stats);
    conv_bnd_kernel<<<dim3(66, EE * 2), dim3(64, 4), 0, stream>>>(inp, emb_w, emb_b, xbuf, stats);
    ln_stats_kernel<<<1, 64, 0, stream>>>(stats);
    scores_fused_kernel<<<1024, 256, 0, stream>>>(xbuf, ln_w, ln_b, wk, wq, stats, sacc);
    softmax_kernel<<<1, 192, 0, stream>>>(sacc, Amat);
    final_kernel<<<(HWP + 127) / 128, 256, 0, stream>>>(xbuf, ln_w, ln_b, wv, wo, bo,
                                                        w_out, b_out, stats, Amat, y);
}